// Round 4
// baseline (139.634 us; speedup 1.0000x reference)
//
#include <hip/hip_runtime.h>

// VQ via MFMA: x (32,64,64,64) fp32 NCHW, embed (512,64) fp32.
// fp16 MFMA approx dists (err ~0.18 << EPS 0.5), exact fp32 recheck of
// near-min candidates (same fmaf order as R1 scalar kernel) -> exact argmin.
//
// R15 profile (67us, absmax 0): VGPR 68, LDS 31.7KB, Occupancy 28%
// (~2.25 blocks/CU avg), MfmaUtil 4.7, VALUBusy 27, HBM 9.5% peak, no
// spill, conflicts negligible. 68% of issue slots idle; R11->R12 halving
// MFMA changed nothing -> NOT pipe-bound, latency-bound with too little
// co-residency to hide the barrier-coupled phase chain.
//
// R16: ROWS 64->32. Grid 2048->4096 (16 blocks/CU work), LDS 31.7->15.8KB
// (8 blocks/CU = 32 waves = 100% slots), launch_bounds(256,8) forces
// VGPR<=64 (needed for 8 waves/SIMD; est ~50 after dropping 16 A-frag +
// 16 m1/m2 regs). Staging = single 8-load batch (half the latency
// exposure). B-prefetch depth 4->2 (TLP replaces ILP; frees 18 regs).
// Predict: Occupancy 28->55-90, dur 67->35-45us, WRITE_SIZE ~33.3MB
// (spill tripwire), VGPR<=64. If occupancy up but dur >60us -> hidden
// throughput wall, pivot to harness-gap/prep-fusion next.

#define VQ_N 131072
#define VQ_D 64
#define VQ_K 512
#define VQ_HW 4096
#define ROWS 32          // rows per block
#define EPS 0.5f         // prune margin; fp16 worst-case err ~0.18, typ ~0.01
#define QW 256           // queue entries per wave (slots 0..31 = row winners)
#define XH_STR 72        // f16/row (64+8 pad), 144B stride (16B-aligned)
#define X32_STR 69       // floats/row: ODD -> conflict-free staging writes

typedef __attribute__((ext_vector_type(8))) _Float16 half8;
typedef __attribute__((ext_vector_type(4))) float f32x4;

// order-preserving float->uint for the exact-recheck u64 key
static __device__ __forceinline__ unsigned fenc(float f) {
    unsigned u = __float_as_uint(f);
    return u ^ ((unsigned)(((int)u) >> 31) | 0x80000000u);
}
// clear low 9 mantissa bits (decode of embedded-index float keys)
static __device__ __forceinline__ float clr9(float f) {
    return __uint_as_float(__float_as_uint(f) & 0xFFFFFE00u);
}

// prep: embed fp32 -> fp16 (EH); first 512 threads also do e_sq
__global__ __launch_bounds__(256) void vq_prep_kernel(
    const float* __restrict__ embed,
    _Float16* __restrict__ EH, float* __restrict__ esq) {
    int g = blockIdx.x * 256 + threadIdx.x;   // 32768 elems
    EH[g] = (_Float16)embed[g];
    if (g < VQ_K) {
        const float* e = embed + g * VQ_D;
        float p0 = 0.f, p1 = 0.f, p2 = 0.f, p3 = 0.f;
#pragma unroll
        for (int d = 0; d < VQ_D; d += 4) {
            p0 = fmaf(e[d + 0], e[d + 0], p0);
            p1 = fmaf(e[d + 1], e[d + 1], p1);
            p2 = fmaf(e[d + 2], e[d + 2], p2);
            p3 = fmaf(e[d + 3], e[d + 3], p3);
        }
        esq[g] = (p0 + p1) + (p2 + p3);
    }
}

// load B fragment + esq for local code-tile nt into NAMED regs (no arrays)
#define LOADB(nt, F0, F1, ES) {                                    \
    int _eo = (nb + ((nt) << 4) + lrow) * VQ_D + (quad << 3);      \
    F0 = *(const half8*)&EH[_eo];                                  \
    F1 = *(const half8*)&EH[_eo + 32];                             \
    ES = esq[nb + ((nt) << 4) + lrow]; }

// 2-MFMA fp16 dist for row-tile rt + 4-VALU key update
#define PROCESS1(nt, rt, F0, F1, ES) {                                         \
    f32x4 acc = {0.f, 0.f, 0.f, 0.f};                                          \
    acc = __builtin_amdgcn_mfma_f32_16x16x32_f16(AH##rt##0, F0, acc, 0, 0, 0); \
    acc = __builtin_amdgcn_mfma_f32_16x16x32_f16(AH##rt##1, F1, acc, 0, 0, 0); \
    unsigned _nn = (unsigned)(nb + ((nt) << 4) + lrow);  /* global code id */  \
    _Pragma("unroll")                                                          \
    for (int i = 0; i < 4; ++i) {      /* C: col(n)=lane&15, row=quad*4+i */   \
        float v = fmaf(-2.f, acc[i], ES);                                      \
        float kf = __uint_as_float((__float_as_uint(v) & 0xFFFFFE00u) | _nn);  \
        m2[rt][i] = __builtin_amdgcn_fmed3f(kf, m1[rt][i], m2[rt][i]);         \
        m1[rt][i] = fminf(m1[rt][i], kf);                                      \
    } }

#define PROCESS2(nt, F0, F1, ES)     \
    PROCESS1(nt, 0, F0, F1, ES)      \
    PROCESS1(nt, 1, F0, F1, ES)

__global__ __launch_bounds__(256, 8) void vq_mfma_kernel(
    const float* __restrict__ x, const float* __restrict__ embed,
    const float* __restrict__ esq, const _Float16* __restrict__ EH,
    float* __restrict__ out_q, float* __restrict__ out_idx) {
    __shared__ __align__(16) _Float16 XsH[ROWS * XH_STR];        // 4608 B
    __shared__ float Xs32[ROWS * X32_STR];                       // 8832 B
    __shared__ unsigned long long row_best[ROWS];                // 256 B
    __shared__ int qcnt[4];
    __shared__ unsigned short qbuf[4 * QW];                      // 2048 B

    const int t   = threadIdx.x;
    const int n0  = blockIdx.x * ROWS;
    const int b   = n0 >> 12;        // 32 | 4096 -> block stays in one image
    const int hw0 = n0 & 4095;

    const int lane = t & 63;
    const int wave = t >> 6;
    const int lrow = lane & 15;
    const int quad = lane >> 4;
    const int nb   = wave * 128;     // this wave's 128 codes

    if (t < ROWS) row_best[t] = ~0ull;
    if (t < 4) qcnt[t] = ROWS;       // slots 0..31 reserved for row winners

    // ---- prefetch first two B tiles BEFORE the barrier (independent) ----
    half8 fa0, fa1, fb0, fb1;
    float esa, esb;
    LOADB(0, fa0, fa1, esa)
    LOADB(1, fb0, fb1, esb)

    // ---- stage X: one 8-load batch/thread, fp32 (odd stride) + fp16 ----
    {
        const int hw = t & 31;
        const int d0 = (t >> 5) * 8;     // 8 d-values per thread
        const float* xb = x + (size_t)b * (VQ_D * VQ_HW) + hw0 + hw;
        half8 H0;
#pragma unroll
        for (int dd = 0; dd < 8; ++dd) {
            float f = xb[(d0 + dd) * VQ_HW];
            Xs32[hw * X32_STR + d0 + dd] = f;
            H0[dd] = (_Float16)f;
        }
        *(half8*)&XsH[hw * XH_STR + d0] = H0;
    }
    __syncthreads();   // barrier 1

    // ---- A fragments via ds_read_b128, named regs: A[m=lrow][k=quad*8+j] ----
    half8 AH00, AH01, AH10, AH11;
#define LOADA(rt)                                                              \
    AH##rt##0 = *(const half8*)&XsH[(rt * 16 + lrow) * XH_STR + quad * 8];     \
    AH##rt##1 = *(const half8*)&XsH[(rt * 16 + lrow) * XH_STR + 32 + quad * 8];
    LOADA(0) LOADA(1)
#undef LOADA

    float m1[2][4], m2[2][4];
#pragma unroll
    for (int rt = 0; rt < 2; ++rt)
#pragma unroll
        for (int i = 0; i < 4; ++i) {
            m1[rt][i] = __uint_as_float(0x7F800000u);   // +inf (low 9 bits 0)
            m2[rt][i] = __uint_as_float(0x7F800000u);
        }

    // ---- main loop: 8 code-tiles, depth-2 NAMED-reg prefetch ----
#pragma unroll 1
    for (int nt = 0; nt < 8; nt += 2) {
        PROCESS2(nt, fa0, fa1, esa)
        int n2 = (nt + 2 < 8) ? nt + 2 : 7;   // clamped harmless reload
        LOADB(n2, fa0, fa1, esa)
        PROCESS2(nt + 1, fb0, fb1, esb)
        int n3 = (nt + 3 < 8) ? nt + 3 : 7;
        LOADB(n3, fb0, fb1, esb)
    }

    // ---- wave-local row-min over the 16 n-lanes (per rt,i) ----
    float g1[2][4];
#pragma unroll
    for (int rt = 0; rt < 2; ++rt)
#pragma unroll
        for (int i = 0; i < 4; ++i) g1[rt][i] = m1[rt][i];
#pragma unroll
    for (int s = 1; s <= 8; s <<= 1)
#pragma unroll
        for (int rt = 0; rt < 2; ++rt)
#pragma unroll
            for (int i = 0; i < 4; ++i)
                g1[rt][i] = fminf(g1[rt][i], __shfl_xor(g1[rt][i], s));

    // ---- push candidates: winner -> fixed slot m (keys unique, exactly one
    //      lane matches g1); near-tie extras -> atomic slots 32+ ----
#pragma unroll
    for (int rt = 0; rt < 2; ++rt)
#pragma unroll
        for (int i = 0; i < 4; ++i) {
            int m = rt * 16 + quad * 4 + i;            // block-local row 0..31
            float thr = clr9(g1[rt][i]) + EPS;
            if (m1[rt][i] == g1[rt][i]) {
                qbuf[wave * QW + m] = (unsigned short)
                    (((unsigned)m << 9) | (__float_as_uint(m1[rt][i]) & 511u));
            } else if (clr9(m1[rt][i]) <= thr) {
                int id = atomicAdd(&qcnt[wave], 1);
                if (id < QW)
                    qbuf[wave * QW + id] = (unsigned short)
                        (((unsigned)m << 9) | (__float_as_uint(m1[rt][i]) & 511u));
            }
            if (clr9(m2[rt][i]) <= thr) {
                int id = atomicAdd(&qcnt[wave], 1);
                if (id < QW)
                    qbuf[wave * QW + id] = (unsigned short)
                        (((unsigned)m << 9) | (__float_as_uint(m2[rt][i]) & 511u));
            }
        }
    asm volatile("s_waitcnt lgkmcnt(0)");   // wave-local queue visible

    // ---- exact fp32 recheck (same fmaf order as R1 kernel), wave-local ----
    int qc = atomicAdd(&qcnt[wave], 0);
    if (qc > QW) qc = QW;
    for (int qi = lane; qi < qc; qi += 64) {
        unsigned e = qbuf[wave * QW + qi];
        int m = (int)(e >> 9), n = (int)(e & 511u);
        const float4* er = (const float4*)(embed + n * VQ_D);
        const float* xr = &Xs32[m * X32_STR];
        float dot = 0.f;
#pragma unroll
        for (int d4 = 0; d4 < 16; ++d4) {
            float4 ev = er[d4];
            dot = fmaf(xr[4 * d4 + 0], ev.x, dot);
            dot = fmaf(xr[4 * d4 + 1], ev.y, dot);
            dot = fmaf(xr[4 * d4 + 2], ev.z, dot);
            dot = fmaf(xr[4 * d4 + 3], ev.w, dot);
        }
        float v = fmaf(-2.f, dot, esq[n]);
        unsigned long long key =
            (((unsigned long long)fenc(v)) << 32) | (unsigned)n;
        atomicMin(&row_best[m], key);   // exact order; equal dist -> smaller n
    }
    __syncthreads();   // barrier 2: all waves' rechecks done

    // ---- outputs: indices + fully-coalesced quantized rows ----
    if (t < ROWS) out_idx[n0 + t] = (float)(unsigned)(row_best[t] & 0xffffffffu);

#pragma unroll
    for (int it = 0; it < 2; ++it) {
        int o   = it * 1024 + t * 4;          // 32 rows x 64 floats, contiguous
        int row = o >> 6;
        int col = o & 63;
        unsigned k = (unsigned)(row_best[row] & 0xffffffffu);
        float4 val = *(const float4*)(embed + k * VQ_D + col);
        *(float4*)(out_q + (size_t)n0 * VQ_D + o) = val;
    }
}

extern "C" void kernel_launch(void* const* d_in, const int* in_sizes, int n_in,
                              void* d_out, int out_size, void* d_ws, size_t ws_size,
                              hipStream_t stream) {
    const float* x     = (const float*)d_in[0];
    const float* embed = (const float*)d_in[1];
    float* out_q   = (float*)d_out;
    float* out_idx = (float*)d_out + (size_t)VQ_N * VQ_D;

    float* esq    = (float*)d_ws;                           // 512 f
    _Float16* EH  = (_Float16*)((char*)d_ws + 2048);        // 512*64 f16

    vq_prep_kernel<<<(VQ_K * VQ_D) / 256, 256, 0, stream>>>(embed, EH, esq);
    vq_mfma_kernel<<<VQ_N / ROWS, 256, 0, stream>>>(x, embed, esq, EH, out_q, out_idx);
}

// Round 5
// 130.121 us; speedup vs baseline: 1.0731x; 1.0731x over previous
//
#include <hip/hip_runtime.h>

// VQ via MFMA: x (32,64,64,64) fp32 NCHW, embed (512,64) fp32.
// fp16 MFMA approx dists (err ~0.18 << EPS 0.5), exact fp32 recheck of
// near-min candidates (bit-identical dot+esq formulas) -> exact argmin.
//
// R16 post-mortem: occupancy 28->67% with dur UNCHANGED (69us) refutes the
// occupancy theory. R11/R12/R15/R16 (2x MFMA, 2x B-traffic, 2x block size,
// 2.4x occupancy, +spill) ALL land 67-69us; no pipe >30%. -> wall is
// per-block fixed latency x block count + per-dispatch overhead.
//
// R17: AMORTIZE. Single fused kernel (prep dispatch deleted):
//  - grid 512 blocks (was 2048+4096); each block does 8 row-tiles of 32.
//  - wave's 128 codes live in 64 VGPR of fp16 B-frags, built once from
//    embed fp32 (same RTE casts as prep) -> hot loop has ZERO memory ops.
//  - esq computed cooperatively in-kernel (EXACT prep formula, p0..p3
//    quad-split) into LDS; recheck reads esq_s (bit-identical values).
//  - per-tile epilogue identical to verified R16 (keys/EPS/atomicMin).
// Predict: 1 dispatch, VGPR ~120-128, LDS ~17.8KB, dur 69 -> 30-45us,
// WRITE ~33.3MB (>37 => spill tripwire), FETCH 18-24MB. If dur stays ~69
// with 8x fewer blocks + 1 dispatch -> external floor (clock/harness).

#define VQ_N 131072
#define VQ_D 64
#define VQ_K 512
#define VQ_HW 4096
#define ROWS 32          // rows per tile
#define TILES 8          // row-tiles per block; grid = N/(ROWS*TILES) = 512
#define EPS 0.5f         // prune margin; fp16 worst-case err ~0.18, typ ~0.01
#define QW 256           // queue entries per wave (slots 0..31 = row winners)
#define XH_STR 72        // f16/row (64+8 pad), 144B stride (16B-aligned)
#define X32_STR 69       // floats/row: ODD -> conflict-free staging writes

typedef __attribute__((ext_vector_type(8))) _Float16 half8;
typedef __attribute__((ext_vector_type(4))) float f32x4;

// order-preserving float->uint for the exact-recheck u64 key
static __device__ __forceinline__ unsigned fenc(float f) {
    unsigned u = __float_as_uint(f);
    return u ^ ((unsigned)(((int)u) >> 31) | 0x80000000u);
}
// clear low 9 mantissa bits (decode of embedded-index float keys)
static __device__ __forceinline__ float clr9(float f) {
    return __uint_as_float(__float_as_uint(f) & 0xFFFFFE00u);
}

// build B fragment pair for code-tile nt from embed fp32 (RTE casts, same
// values as the old prep kernel's EH)
#define LOADBF(nt, F0, F1) {                                                   \
    const float* _er = embed + (size_t)(nb + ((nt) << 4) + lrow) * VQ_D        \
                       + (quad << 3);                                          \
    float4 _a = *(const float4*)_er;                                           \
    float4 _b2 = *(const float4*)(_er + 4);                                    \
    float4 _c = *(const float4*)(_er + 32);                                    \
    float4 _d2 = *(const float4*)(_er + 36);                                   \
    F0[0] = (_Float16)_a.x;  F0[1] = (_Float16)_a.y;                           \
    F0[2] = (_Float16)_a.z;  F0[3] = (_Float16)_a.w;                           \
    F0[4] = (_Float16)_b2.x; F0[5] = (_Float16)_b2.y;                          \
    F0[6] = (_Float16)_b2.z; F0[7] = (_Float16)_b2.w;                          \
    F1[0] = (_Float16)_c.x;  F1[1] = (_Float16)_c.y;                           \
    F1[2] = (_Float16)_c.z;  F1[3] = (_Float16)_c.w;                           \
    F1[4] = (_Float16)_d2.x; F1[5] = (_Float16)_d2.y;                          \
    F1[6] = (_Float16)_d2.z; F1[7] = (_Float16)_d2.w; }

// 2-MFMA fp16 dist for row-tile rt + 4-VALU key update (verified R15/R16)
#define PROCESS1(nt, rt, F0, F1, ES) {                                         \
    f32x4 acc = {0.f, 0.f, 0.f, 0.f};                                          \
    acc = __builtin_amdgcn_mfma_f32_16x16x32_f16(AH##rt##0, F0, acc, 0, 0, 0); \
    acc = __builtin_amdgcn_mfma_f32_16x16x32_f16(AH##rt##1, F1, acc, 0, 0, 0); \
    unsigned _nn = (unsigned)(nb + ((nt) << 4) + lrow);  /* global code id */  \
    _Pragma("unroll")                                                          \
    for (int i = 0; i < 4; ++i) {      /* C: col(n)=lane&15, row=quad*4+i */   \
        float v = fmaf(-2.f, acc[i], ES);                                      \
        float kf = __uint_as_float((__float_as_uint(v) & 0xFFFFFE00u) | _nn);  \
        m2[rt][i] = __builtin_amdgcn_fmed3f(kf, m1[rt][i], m2[rt][i]);         \
        m1[rt][i] = fminf(m1[rt][i], kf);                                      \
    } }

#define PROCESS2(nt, F0, F1, ES)     \
    PROCESS1(nt, 0, F0, F1, ES)      \
    PROCESS1(nt, 1, F0, F1, ES)

__global__ __launch_bounds__(256, 2) void vq_fused_kernel(
    const float* __restrict__ x, const float* __restrict__ embed,
    float* __restrict__ out_q, float* __restrict__ out_idx) {
    __shared__ __align__(16) _Float16 XsH[ROWS * XH_STR];        // 4608 B
    __shared__ float Xs32[ROWS * X32_STR];                       // 8832 B
    __shared__ float esq_s[VQ_K];                                // 2048 B
    __shared__ unsigned long long row_best[ROWS];                // 256 B
    __shared__ int qcnt[4];
    __shared__ unsigned short qbuf[4 * QW];                      // 2048 B

    const int t    = threadIdx.x;
    const int n0b  = blockIdx.x * (ROWS * TILES);   // 256 rows per block
    const int b    = n0b >> 12;      // 256 | 4096 -> block stays in one image
    const int hwb  = n0b & 4095;

    const int lane = t & 63;
    const int wave = t >> 6;
    const int lrow = lane & 15;
    const int quad = lane >> 4;
    const int nb   = wave * 128;     // this wave's 128 codes

    // ---- build wave's 128 codes as fp16 B-frags in registers (once) ----
    half8 B00, B01, B10, B11, B20, B21, B30, B31;
    half8 B40, B41, B50, B51, B60, B61, B70, B71;
    LOADBF(0, B00, B01) LOADBF(1, B10, B11)
    LOADBF(2, B20, B21) LOADBF(3, B30, B31)
    LOADBF(4, B40, B41) LOADBF(5, B50, B51)
    LOADBF(6, B60, B61) LOADBF(7, B70, B71)

    // ---- cooperative exact esq into LDS: thread t -> codes t, t+256.
    //      EXACT prep-kernel formula (p0..p3 quad-split) -> bit-identical ----
#pragma unroll
    for (int h = 0; h < 2; ++h) {
        const int c = t + h * 256;
        const float* e = embed + (size_t)c * VQ_D;
        float p0 = 0.f, p1 = 0.f, p2 = 0.f, p3 = 0.f;
#pragma unroll
        for (int d = 0; d < VQ_D; d += 4) {
            p0 = fmaf(e[d + 0], e[d + 0], p0);
            p1 = fmaf(e[d + 1], e[d + 1], p1);
            p2 = fmaf(e[d + 2], e[d + 2], p2);
            p3 = fmaf(e[d + 3], e[d + 3], p3);
        }
        esq_s[c] = (p0 + p1) + (p2 + p3);
    }
    __syncthreads();   // esq_s ready

    float es0 = esq_s[nb + 0 * 16 + lrow], es1 = esq_s[nb + 1 * 16 + lrow];
    float es2 = esq_s[nb + 2 * 16 + lrow], es3 = esq_s[nb + 3 * 16 + lrow];
    float es4 = esq_s[nb + 4 * 16 + lrow], es5 = esq_s[nb + 5 * 16 + lrow];
    float es6 = esq_s[nb + 6 * 16 + lrow], es7 = esq_s[nb + 7 * 16 + lrow];

    // ---- 8 row-tiles of 32 rows, all sharing the in-register codebook ----
#pragma unroll 1
    for (int tile = 0; tile < TILES; ++tile) {
        const int n0  = n0b + tile * ROWS;
        const int hw0 = hwb + tile * ROWS;

        if (t < ROWS) row_best[t] = ~0ull;
        if (t < 4) qcnt[t] = ROWS;   // slots 0..31 reserved for row winners

        // stage X: fp32 (odd stride) + fp16 (b128), 8 d-values per thread
        {
            const int hw = t & 31;
            const int d0 = (t >> 5) * 8;
            const float* xb = x + (size_t)b * (VQ_D * VQ_HW) + hw0 + hw;
            half8 H0;
#pragma unroll
            for (int dd = 0; dd < 8; ++dd) {
                float f = xb[(d0 + dd) * VQ_HW];
                Xs32[hw * X32_STR + d0 + dd] = f;
                H0[dd] = (_Float16)f;
            }
            *(half8*)&XsH[hw * XH_STR + d0] = H0;
        }
        __syncthreads();   // barrier 1: stage + reinit visible

        // A fragments via ds_read_b128: A[m=lrow][k=quad*8+j]
        half8 AH00, AH01, AH10, AH11;
#define LOADA(rt)                                                              \
    AH##rt##0 = *(const half8*)&XsH[(rt * 16 + lrow) * XH_STR + quad * 8];     \
    AH##rt##1 = *(const half8*)&XsH[(rt * 16 + lrow) * XH_STR + 32 + quad * 8];
        LOADA(0) LOADA(1)
#undef LOADA

        float m1[2][4], m2[2][4];
#pragma unroll
        for (int rt = 0; rt < 2; ++rt)
#pragma unroll
            for (int i = 0; i < 4; ++i) {
                m1[rt][i] = __uint_as_float(0x7F800000u);   // +inf (low 9b 0)
                m2[rt][i] = __uint_as_float(0x7F800000u);
            }

        // hot loop: zero memory ops, 32 MFMA + 256 VALU
        PROCESS2(0, B00, B01, es0)
        PROCESS2(1, B10, B11, es1)
        PROCESS2(2, B20, B21, es2)
        PROCESS2(3, B30, B31, es3)
        PROCESS2(4, B40, B41, es4)
        PROCESS2(5, B50, B51, es5)
        PROCESS2(6, B60, B61, es6)
        PROCESS2(7, B70, B71, es7)

        // wave-local row-min over the 16 n-lanes (per rt,i)
        float g1[2][4];
#pragma unroll
        for (int rt = 0; rt < 2; ++rt)
#pragma unroll
            for (int i = 0; i < 4; ++i) g1[rt][i] = m1[rt][i];
#pragma unroll
        for (int s = 1; s <= 8; s <<= 1)
#pragma unroll
            for (int rt = 0; rt < 2; ++rt)
#pragma unroll
                for (int i = 0; i < 4; ++i)
                    g1[rt][i] = fminf(g1[rt][i], __shfl_xor(g1[rt][i], s));

        // push candidates: winner -> fixed slot m; near-ties -> slots 32+
#pragma unroll
        for (int rt = 0; rt < 2; ++rt)
#pragma unroll
            for (int i = 0; i < 4; ++i) {
                int m = rt * 16 + quad * 4 + i;        // block-local row 0..31
                float thr = clr9(g1[rt][i]) + EPS;
                if (m1[rt][i] == g1[rt][i]) {
                    qbuf[wave * QW + m] = (unsigned short)
                        (((unsigned)m << 9) |
                         (__float_as_uint(m1[rt][i]) & 511u));
                } else if (clr9(m1[rt][i]) <= thr) {
                    int id = atomicAdd(&qcnt[wave], 1);
                    if (id < QW)
                        qbuf[wave * QW + id] = (unsigned short)
                            (((unsigned)m << 9) |
                             (__float_as_uint(m1[rt][i]) & 511u));
                }
                if (clr9(m2[rt][i]) <= thr) {
                    int id = atomicAdd(&qcnt[wave], 1);
                    if (id < QW)
                        qbuf[wave * QW + id] = (unsigned short)
                            (((unsigned)m << 9) |
                             (__float_as_uint(m2[rt][i]) & 511u));
                }
            }
        asm volatile("s_waitcnt lgkmcnt(0)");   // wave-local queue visible

        // exact fp32 recheck (same fmaf order as R1 kernel), wave-local
        int qc = atomicAdd(&qcnt[wave], 0);
        if (qc > QW) qc = QW;
        for (int qi = lane; qi < qc; qi += 64) {
            unsigned e = qbuf[wave * QW + qi];
            int m = (int)(e >> 9), n = (int)(e & 511u);
            const float4* er = (const float4*)(embed + n * VQ_D);
            const float* xr = &Xs32[m * X32_STR];
            float dot = 0.f;
#pragma unroll
            for (int d4 = 0; d4 < 16; ++d4) {
                float4 ev = er[d4];
                dot = fmaf(xr[4 * d4 + 0], ev.x, dot);
                dot = fmaf(xr[4 * d4 + 1], ev.y, dot);
                dot = fmaf(xr[4 * d4 + 2], ev.z, dot);
                dot = fmaf(xr[4 * d4 + 3], ev.w, dot);
            }
            float v = fmaf(-2.f, dot, esq_s[n]);
            unsigned long long key =
                (((unsigned long long)fenc(v)) << 32) | (unsigned)n;
            atomicMin(&row_best[m], key);  // exact; equal dist -> smaller n
        }
        __syncthreads();   // barrier 2: all waves' rechecks done

        // outputs: indices + fully-coalesced quantized rows
        if (t < ROWS)
            out_idx[n0 + t] = (float)(unsigned)(row_best[t] & 0xffffffffu);

#pragma unroll
        for (int it = 0; it < 2; ++it) {
            int o   = it * 1024 + t * 4;   // 32 rows x 64 floats, contiguous
            int row = o >> 6;
            int col = o & 63;
            unsigned k = (unsigned)(row_best[row] & 0xffffffffu);
            float4 val = *(const float4*)(embed + k * VQ_D + col);
            *(float4*)(out_q + (size_t)n0 * VQ_D + o) = val;
        }
        __syncthreads();   // barrier 3: outputs done before next-tile reinit
    }
}

extern "C" void kernel_launch(void* const* d_in, const int* in_sizes, int n_in,
                              void* d_out, int out_size, void* d_ws, size_t ws_size,
                              hipStream_t stream) {
    const float* x     = (const float*)d_in[0];
    const float* embed = (const float*)d_in[1];
    float* out_q   = (float*)d_out;
    float* out_idx = (float*)d_out + (size_t)VQ_N * VQ_D;

    vq_fused_kernel<<<VQ_N / (ROWS * TILES), 256, 0, stream>>>(
        x, embed, out_q, out_idx);
}